// Round 7
// baseline (582.294 us; speedup 1.0000x reference)
//
#include <hip/hip_runtime.h>

// Problem constants
#define B_ 8
#define L_ 128
#define D_ 768
#define D4 (D_ / 4)               // 192 float4 columns
#define IT 16                     // i-rows per block (contiguity tile)
#define JC 8                      // j's per block
#define NS (L_ / JC)              // 16 j-chunks -> 16 partial buffers

typedef float v4f __attribute__((ext_vector_type(4)));

// ---------------------------------------------------------------------------
// Kernel A: i-tiled partial aggregation.
//   P[s][b*L+i][d] = sum_{j in chunk s} adj[b,i,j] * (text[b,j,d] + dep[b,j,i,d])
// Block = (b, i-tile of 16 rows, j-chunk of 8). Per j-step the block reads
// dep[b,j,i0:i0+16,0:768] = 48 KB FULLY CONTIGUOUS (vs 6 KB before), and the
// 8 consecutive blockIdx (same b,s; varying i-tile) collectively cover the
// whole 384 KB j-slab in order. 256 threads (16 waves/CU at 4 blocks/CU);
// each thread owns 12 (i, d4) cells and issues 15 independent plain loads
// per j-step (NT dropped: zero-reuse data, plain loads match the 6.3 TB/s
// copy benchmark config). j-loop fully unrolled for compiler pipelining.
// ---------------------------------------------------------------------------
__global__ __launch_bounds__(256) void agg_kernel(
    const float* __restrict__ text,       // [B][L][D]
    const float* __restrict__ adj,        // [B][L][L]
    const float* __restrict__ dep,        // [B][L][L][D]
    float* __restrict__ P) {              // [NS][B*L][D] partials
  const int bx = blockIdx.x;              // [b:3][s:4][it:3] -> it fastest
  const int it = bx & 7;
  const int s  = (bx >> 3) & 15;
  const int b  = bx >> 7;
  const int i0 = it * IT;
  const int j0 = s * JC;
  const int t  = threadIdx.x;             // 0..255
  const int iq = t >> 6;                  // wave index 0..3 -> i group
  const int dq = t & 63;                  // lane -> base d4 column

  __shared__ float adj_s[JC][IT];
  if (t < JC * IT) {
    const int j = t >> 4;
    const int i = t & 15;
    adj_s[j][i] = adj[((size_t)b * L_ + i0 + i) * L_ + j0 + j];
  }
  __syncthreads();

  const v4f* dep4  = (const v4f*)dep + ((size_t)b * L_ + j0) * L_ * D4;
  const v4f* text4 = (const v4f*)text + ((size_t)b * L_ + j0) * D4;

  v4f acc[4][3] = {};                     // 12 cells: i = iq+4k, d4 = dq+64c

#pragma unroll
  for (int j = 0; j < JC; ++j) {
    float a[4];
#pragma unroll
    for (int k = 0; k < 4; ++k) a[k] = adj_s[j][iq + 4 * k];

    v4f tx[3];
#pragma unroll
    for (int c = 0; c < 3; ++c) tx[c] = text4[(size_t)j * D4 + dq + 64 * c];

#pragma unroll
    for (int k = 0; k < 4; ++k) {
      const v4f* drow = dep4 + ((size_t)j * L_ + i0 + iq + 4 * k) * D4;
#pragma unroll
      for (int c = 0; c < 3; ++c) {
        const v4f dv = drow[dq + 64 * c];
        acc[k][c] += a[k] * (tx[c] + dv);
      }
    }
  }

  float* Pb = P + ((size_t)s * (B_ * L_) + (size_t)b * L_ + i0) * D_;
#pragma unroll
  for (int k = 0; k < 4; ++k)
#pragma unroll
    for (int c = 0; c < 3; ++c)
      ((v4f*)Pb)[(size_t)(iq + 4 * k) * D4 + dq + 64 * c] = acc[k][c];
}

// ---------------------------------------------------------------------------
// Kernel R: agg[m][d] = sum_s P[s][m][d]. 48 MB just-written (L3-resident)
// + 3 MB write. 768 blocks x 256 threads, one float4 per thread.
// ---------------------------------------------------------------------------
__global__ __launch_bounds__(256) void reduce_kernel(
    const float* __restrict__ P,          // [NS][M][D]
    float* __restrict__ agg) {            // [M][D]
  const size_t idx = (size_t)blockIdx.x * 256 + threadIdx.x;  // v4f index
  const v4f* P4 = (const v4f*)P;
  v4f sum = P4[idx];
#pragma unroll
  for (int k = 1; k < NS; ++k) sum += P4[(size_t)k * ((size_t)B_ * L_ * D4) + idx];
  ((v4f*)agg)[idx] = sum;
}

// ---------------------------------------------------------------------------
// Kernel B: out[m][n] = relu( sum_k agg[m][k] * W[k][n] + bias[n] )
// M=1024, N=768, K=768. 32x64 tile -> 384 blocks. Register prefetch of the
// next K-tile issued right after the LDS-write barrier. A-tile transposed
// [TK][TM+2] for conflict-free writes and float2 fragment reads.
// ---------------------------------------------------------------------------
#define TM 32
#define TN 64
#define TK 32
#define NKT (D_ / TK)                     // 24 K-tiles

__global__ __launch_bounds__(256) void gemm_bias_relu(
    const float* __restrict__ A,          // [M][K]  (agg)
    const float* __restrict__ W,          // [K][N]
    const float* __restrict__ bias,       // [N]
    float* __restrict__ out) {            // [M][N]
  __shared__ float AsT[TK][TM + 2];       // transposed A tile
  __shared__ float Bs[TK][TN];

  const int tid = threadIdx.x;
  const int tx  = tid & 15;               // n-direction (16 x float4 = 64)
  const int ty  = tid >> 4;               // m-direction (16 x 2 rows = 32)
  const int m0  = blockIdx.y * TM;
  const int n0  = blockIdx.x * TN;

  // loader indices
  const int ar  = tid >> 3;               // 0..31  A row
  const int ac  = (tid & 7) * 4;          // float4 k-col within K-tile
  const int br  = tid >> 4;               // 0..15  W row in K-tile (+16 second)
  const int bc  = (tid & 15) * 4;         // float4 n-col within N-tile

  const float* Arow  = A + (size_t)(m0 + ar) * D_ + ac;
  const float* Wrow0 = W + (size_t)br * D_ + n0 + bc;
  const float* Wrow1 = W + (size_t)(br + 16) * D_ + n0 + bc;

  float acc[2][4] = {};

  // prefetch tile 0
  v4f a_reg  = *(const v4f*)Arow;
  v4f b_reg0 = *(const v4f*)Wrow0;
  v4f b_reg1 = *(const v4f*)Wrow1;

  for (int t = 0; t < NKT; ++t) {
    __syncthreads();                      // previous tile's reads done
    AsT[ac + 0][ar] = a_reg.x;
    AsT[ac + 1][ar] = a_reg.y;
    AsT[ac + 2][ar] = a_reg.z;
    AsT[ac + 3][ar] = a_reg.w;
    *(v4f*)&Bs[br][bc]      = b_reg0;
    *(v4f*)&Bs[br + 16][bc] = b_reg1;
    __syncthreads();

    // issue next tile's loads now; they complete under the compute below
    if (t + 1 < NKT) {
      a_reg  = *(const v4f*)(Arow + (t + 1) * TK);
      b_reg0 = *(const v4f*)(Wrow0 + (size_t)(t + 1) * TK * D_);
      b_reg1 = *(const v4f*)(Wrow1 + (size_t)(t + 1) * TK * D_);
    }

#pragma unroll
    for (int kk = 0; kk < TK; ++kk) {
      const float2 av = *(const float2*)&AsT[kk][ty * 2];
      const v4f    bv = *(const v4f*)&Bs[kk][tx * 4];
#pragma unroll
      for (int pn = 0; pn < 4; ++pn) {
        acc[0][pn] += av.x * bv[pn];
        acc[1][pn] += av.y * bv[pn];
      }
    }
  }

  const v4f bvec = *(const v4f*)&bias[n0 + tx * 4];
#pragma unroll
  for (int pm = 0; pm < 2; ++pm) {
    v4f o;
#pragma unroll
    for (int pn = 0; pn < 4; ++pn) o[pn] = fmaxf(acc[pm][pn] + bvec[pn], 0.f);
    *(v4f*)&out[(size_t)(m0 + ty * 2 + pm) * D_ + n0 + tx * 4] = o;
  }
}

extern "C" void kernel_launch(void* const* d_in, const int* in_sizes, int n_in,
                              void* d_out, int out_size, void* d_ws, size_t ws_size,
                              hipStream_t stream) {
  const float* text   = (const float*)d_in[0];  // [B][L][D]
  const float* adj    = (const float*)d_in[1];  // [B][L][L]
  const float* dep    = (const float*)d_in[2];  // [B][L][L][D]
  const float* weight = (const float*)d_in[3];  // [D][D]
  const float* bias   = (const float*)d_in[4];  // [D]
  float* out = (float*)d_out;                   // [B][L][D]

  float* P    = (float*)d_ws;                   // [NS][B*L][D] = 48 MB
  float* aggb = P + (size_t)NS * B_ * L_ * D_;  // [B*L][D] = 3 MB

  agg_kernel<<<B_ * L_ * NS / IT, 256, 0, stream>>>(text, adj, dep, P);  // 1024 blocks
  reduce_kernel<<<(B_ * L_ * D4) / 256, 256, 0, stream>>>(P, aggb);      // 768 blocks

  dim3 grid(D_ / TN, (B_ * L_) / TM);           // 12 x 32 = 384 blocks
  gemm_bias_relu<<<grid, 256, 0, stream>>>(aggb, weight, bias, out);
}